// Round 2
// baseline (1109.463 us; speedup 1.0000x reference)
//
#include <hip/hip_runtime.h>
#include <cmath>

#define TS 256

constexpr int S    = 95;
constexpr int B    = 2;
constexpr int S3   = S * S * S;          // 857375
constexpr int S1   = 47;
constexpr int S13  = S1 * S1 * S1;       // 103823
constexpr int NPTS = 40000;
constexpr int C0   = 8;
constexpr int C1   = 16;
constexpr float EPS = 1e-4f;
constexpr int NB_STATS = 128;

// ---------------- scatter ----------------
__global__ void k_scatter(const int* __restrict__ coords, const float* __restrict__ feats,
                          float* __restrict__ grid, float* __restrict__ mask) {
    int i = blockIdx.x * blockDim.x + threadIdx.x;
    if (i >= NPTS) return;
    int x = coords[i * 4 + 0], y = coords[i * 4 + 1], z = coords[i * 4 + 2], b = coords[i * 4 + 3];
    int v = ((b * S + x) * S + y) * S + z;
    atomicAdd(&grid[v], feats[i]);
    mask[v] = 1.0f;   // benign race: all writers store 1.0
}

// ---------------- active-list compaction (L0) ----------------
__global__ void k_list0(const float* __restrict__ mask, int* __restrict__ list, int* __restrict__ cnt) {
    int v = blockIdx.x * blockDim.x + threadIdx.x;
    if (v >= B * S3) return;
    if (mask[v] != 0.0f) {
        int idx = atomicAdd(cnt, 1);
        list[idx] = v;
    }
}

// ---------------- conv0: 1 -> 8, SAME, stride 1 ----------------
__global__ void k_conv0(const float* __restrict__ grid,
                        const int* __restrict__ list, const int* __restrict__ cnt,
                        const float* __restrict__ w, float* __restrict__ out) {
    int i = blockIdx.x * blockDim.x + threadIdx.x;
    if (i >= cnt[0]) return;
    int v = list[i];
    int z = v % S; int t = v / S;
    int y = t % S; t /= S;
    int x = t % S; int b = t / S;
    float acc[C0];
#pragma unroll
    for (int c = 0; c < C0; ++c) acc[c] = 0.f;
    for (int kx = 0; kx < 3; ++kx) {
        int xx = x + kx - 1; if ((unsigned)xx >= (unsigned)S) continue;
        for (int ky = 0; ky < 3; ++ky) {
            int yy = y + ky - 1; if ((unsigned)yy >= (unsigned)S) continue;
            for (int kz = 0; kz < 3; ++kz) {
                int zz = z + kz - 1; if ((unsigned)zz >= (unsigned)S) continue;
                int n = ((b * S + xx) * S + yy) * S + zz;
                float g = grid[n];          // grid is exactly 0 off-mask
                if (g != 0.0f) {
                    const float* wp = &w[((kx * 3 + ky) * 3 + kz) * C0];
#pragma unroll
                    for (int c = 0; c < C0; ++c) acc[c] = fmaf(g, wp[c], acc[c]);
                }
            }
        }
    }
#pragma unroll
    for (int c = 0; c < C0; ++c) out[(size_t)i * C0 + c] = acc[c];
}

// ---------------- BN statistics: partial sums over active list ----------------
template <int C>
__global__ void k_stats(const float* __restrict__ xs, const int* __restrict__ cnt,
                        float* __restrict__ partial) {
    int n = cnt[0];
    float s[2 * C];
#pragma unroll
    for (int c = 0; c < 2 * C; ++c) s[c] = 0.f;
    int stride = gridDim.x * blockDim.x;
    for (int i = blockIdx.x * blockDim.x + threadIdx.x; i < n; i += stride) {
#pragma unroll
        for (int c = 0; c < C; ++c) {
            float v = xs[(size_t)i * C + c];
            s[c] += v;
            s[C + c] += v * v;
        }
    }
#pragma unroll
    for (int c = 0; c < 2 * C; ++c)
        for (int off = 32; off > 0; off >>= 1)
            s[c] += __shfl_down(s[c], off, 64);
    __shared__ float ls[4][2 * C];
    int wv = threadIdx.x >> 6, ln = threadIdx.x & 63;
    if (ln == 0) {
#pragma unroll
        for (int c = 0; c < 2 * C; ++c) ls[wv][c] = s[c];
    }
    __syncthreads();
    if (threadIdx.x < 2 * C) {
        float t = ls[0][threadIdx.x] + ls[1][threadIdx.x] + ls[2][threadIdx.x] + ls[3][threadIdx.x];
        partial[blockIdx.x * (2 * C) + threadIdx.x] = t;
    }
}

// ---------------- BN finalize: per-channel scale/shift ----------------
template <int C>
__global__ void k_finalize(const float* __restrict__ partial, const int* __restrict__ cnt,
                           const float* __restrict__ gamma, const float* __restrict__ beta,
                           float* __restrict__ scsh) {
    int c = threadIdx.x;
    if (c >= C) return;
    float s = 0.f, ss = 0.f;
    for (int k = 0; k < NB_STATS; ++k) {
        s  += partial[k * 2 * C + c];
        ss += partial[k * 2 * C + C + c];
    }
    float n = fmaxf((float)cnt[0], 1.0f);
    float mean = s / n;
    float var  = ss / n - mean * mean;
    float sc = gamma[c] * rsqrtf(var + EPS);
    scsh[c]     = sc;
    scsh[C + c] = beta[c] - mean * sc;
}

// ---------------- BN apply + ReLU: sparse x -> dense y (+ optional sparse copy) ----------------
template <int C>
__global__ void k_bnapply(const float* __restrict__ xs, const int* __restrict__ list,
                          const int* __restrict__ cnt, const float* __restrict__ scsh,
                          float* __restrict__ yd, float* __restrict__ xs_out) {
    int i = blockIdx.x * blockDim.x + threadIdx.x;
    if (i >= cnt[0]) return;
    int v = list[i];
#pragma unroll
    for (int c = 0; c < C; ++c) {
        float val = fmaf(scsh[c], xs[(size_t)i * C + c], scsh[C + c]);
        val = fmaxf(val, 0.f);
        yd[(size_t)v * C + c] = val;
        if (xs_out) xs_out[(size_t)i * C + c] = val;
    }
}

// ---------------- generic 3x3x3 SAME stride-1 conv at active voxels ----------------
template <int CIN, int COUT, int SG>
__global__ void k_conv(const float* __restrict__ y, const float* __restrict__ mask,
                       const int* __restrict__ list, const int* __restrict__ cnt,
                       const float* __restrict__ w, const float* __restrict__ res,
                       float* __restrict__ out) {
    int i = blockIdx.x * blockDim.x + threadIdx.x;
    if (i >= cnt[0]) return;
    int v = list[i];
    int z = v % SG; int t = v / SG;
    int yy = t % SG; t /= SG;
    int x = t % SG; int b = t / SG;
    float acc[COUT];
#pragma unroll
    for (int c = 0; c < COUT; ++c) acc[c] = res ? res[(size_t)i * COUT + c] : 0.f;
    for (int kx = 0; kx < 3; ++kx) {
        int xx = x + kx - 1; if ((unsigned)xx >= (unsigned)SG) continue;
        for (int ky = 0; ky < 3; ++ky) {
            int yn = yy + ky - 1; if ((unsigned)yn >= (unsigned)SG) continue;
            for (int kz = 0; kz < 3; ++kz) {
                int zz = z + kz - 1; if ((unsigned)zz >= (unsigned)SG) continue;
                int n = ((b * SG + xx) * SG + yn) * SG + zz;
                if (mask[n] != 0.f) {
                    const float* yp = &y[(size_t)n * CIN];
                    const float* wp = &w[((kx * 3 + ky) * 3 + kz) * CIN * COUT];
#pragma unroll
                    for (int ci = 0; ci < CIN; ++ci) {
                        float val = yp[ci];
#pragma unroll
                        for (int co = 0; co < COUT; ++co)
                            acc[co] = fmaf(val, wp[ci * COUT + co], acc[co]);
                    }
                }
            }
        }
    }
#pragma unroll
    for (int c = 0; c < COUT; ++c) out[(size_t)i * COUT + c] = acc[c];
}

// ---------------- stride-2 VALID conv, L0 dense input -> L1 sparse output ----------------
template <int CIN, int COUT>
__global__ void k_conv_s2(const float* __restrict__ y, const float* __restrict__ mask0,
                          const int* __restrict__ list1, const int* __restrict__ cnt1,
                          const float* __restrict__ w, float* __restrict__ out) {
    int i = blockIdx.x * blockDim.x + threadIdx.x;
    if (i >= cnt1[0]) return;
    int v = list1[i];
    int z = v % S1; int t = v / S1;
    int yy = t % S1; t /= S1;
    int x = t % S1; int b = t / S1;
    float acc[COUT];
#pragma unroll
    for (int c = 0; c < COUT; ++c) acc[c] = 0.f;
    for (int kx = 0; kx < 3; ++kx) {
        int xx = 2 * x + kx;
        for (int ky = 0; ky < 3; ++ky) {
            int yn = 2 * yy + ky;
            for (int kz = 0; kz < 3; ++kz) {
                int zz = 2 * z + kz;
                int n = ((b * S + xx) * S + yn) * S + zz;
                if (mask0[n] != 0.f) {
                    const float* yp = &y[(size_t)n * CIN];
                    const float* wp = &w[((kx * 3 + ky) * 3 + kz) * CIN * COUT];
#pragma unroll
                    for (int ci = 0; ci < CIN; ++ci) {
                        float val = yp[ci];
#pragma unroll
                        for (int co = 0; co < COUT; ++co)
                            acc[co] = fmaf(val, wp[ci * COUT + co], acc[co]);
                    }
                }
            }
        }
    }
#pragma unroll
    for (int c = 0; c < COUT; ++c) out[(size_t)i * COUT + c] = acc[c];
}

// ---------------- downsampled mask + list (L1) ----------------
__global__ void k_mask1(const float* __restrict__ mask0, float* __restrict__ mask1,
                        int* __restrict__ list1, int* __restrict__ cnt1) {
    int v = blockIdx.x * blockDim.x + threadIdx.x;
    if (v >= B * S13) return;
    int z = v % S1; int t = v / S1;
    int y = t % S1; t /= S1;
    int x = t % S1; int b = t / S1;
    float m = 0.f;
    for (int kx = 0; kx < 3; ++kx)
        for (int ky = 0; ky < 3; ++ky)
            for (int kz = 0; kz < 3; ++kz) {
                int n = ((b * S + 2 * x + kx) * S + 2 * y + ky) * S + 2 * z + kz;
                m = fmaxf(m, mask0[n]);
            }
    mask1[v] = m;
    if (m > 0.f) {
        int idx = atomicAdd(cnt1, 1);
        list1[idx] = v;
    }
}

// ---------------- masked max-pool + 2-layer MLP head ----------------
__global__ void k_pool(const float* __restrict__ x1s, const int* __restrict__ list1,
                       const int* __restrict__ cnt1,
                       const float* __restrict__ l1w, const float* __restrict__ l1b,
                       const float* __restrict__ l2w, const float* __restrict__ l2b,
                       float* __restrict__ outp) {
    int b = blockIdx.x;
    float mx[C1];
#pragma unroll
    for (int c = 0; c < C1; ++c) mx[c] = -INFINITY;
    int n = cnt1[0];
    for (int i = threadIdx.x; i < n; i += blockDim.x) {
        int v = list1[i];
        if (v / S13 == b) {
#pragma unroll
            for (int c = 0; c < C1; ++c) mx[c] = fmaxf(mx[c], x1s[(size_t)i * C1 + c]);
        }
    }
#pragma unroll
    for (int c = 0; c < C1; ++c)
        for (int off = 32; off > 0; off >>= 1)
            mx[c] = fmaxf(mx[c], __shfl_down(mx[c], off, 64));
    __shared__ float sm[4][C1];
    int wv = threadIdx.x >> 6, ln = threadIdx.x & 63;
    if (ln == 0) {
#pragma unroll
        for (int c = 0; c < C1; ++c) sm[wv][c] = mx[c];
    }
    __syncthreads();
    if (threadIdx.x == 0) {
        float pooled[C1];
#pragma unroll
        for (int c = 0; c < C1; ++c) {
            float m = fmaxf(fmaxf(sm[0][c], sm[1][c]), fmaxf(sm[2][c], sm[3][c]));
            pooled[c] = (m == -INFINITY) ? 0.f : m;
        }
        float o = l2b[0];
        for (int j = 0; j < 32; ++j) {
            float h = l1b[j];
#pragma unroll
            for (int c = 0; c < C1; ++c) h = fmaf(l1w[j * C1 + c], pooled[c], h);
            o = fmaf(l2w[j], h, o);
        }
        outp[b] = o;
    }
}

// ---------------- host-side BN helper ----------------
template <int C>
static void run_bn(const float* xs, const float* g, const float* bt,
                   const int* cntp, const int* listp, float* yd, float* xs_out, int maxn,
                   float* partial, float* scsh, hipStream_t stream) {
    k_stats<C><<<NB_STATS, TS, 0, stream>>>(xs, cntp, partial);
    k_finalize<C><<<1, 64, 0, stream>>>(partial, cntp, g, bt, scsh);
    k_bnapply<C><<<(maxn + TS - 1) / TS, TS, 0, stream>>>(xs, listp, cntp, scsh, yd, xs_out);
}

extern "C" void kernel_launch(void* const* d_in, const int* in_sizes, int n_in,
                              void* d_out, int out_size, void* d_ws, size_t ws_size,
                              hipStream_t stream) {
    const int*   coords = (const int*)  d_in[0];
    const float* feats  = (const float*)d_in[1];
    const float* w0     = (const float*)d_in[2];
    const float* g0     = (const float*)d_in[3];
    const float* b0     = (const float*)d_in[4];
    const float* ba0_g1 = (const float*)d_in[5];
    const float* ba0_b1 = (const float*)d_in[6];
    const float* ba0_w1 = (const float*)d_in[7];
    const float* ba0_g2 = (const float*)d_in[8];
    const float* ba0_b2 = (const float*)d_in[9];
    const float* ba0_w2 = (const float*)d_in[10];
    const float* ba1_g1 = (const float*)d_in[11];
    const float* ba1_b1 = (const float*)d_in[12];
    const float* ba1_w1 = (const float*)d_in[13];
    const float* ba1_g2 = (const float*)d_in[14];
    const float* ba1_b2 = (const float*)d_in[15];
    const float* ba1_w2 = (const float*)d_in[16];
    const float* bo0_g1 = (const float*)d_in[17];
    const float* bo0_b1 = (const float*)d_in[18];
    const float* bo0_w1 = (const float*)d_in[19];
    const float* bo0_g2 = (const float*)d_in[20];
    const float* bo0_b2 = (const float*)d_in[21];
    const float* bo0_w2 = (const float*)d_in[22];
    const float* bo1_g1 = (const float*)d_in[23];
    const float* bo1_b1 = (const float*)d_in[24];
    const float* bo1_w1 = (const float*)d_in[25];
    const float* bo1_g2 = (const float*)d_in[26];
    const float* bo1_b2 = (const float*)d_in[27];
    const float* bo1_w2 = (const float*)d_in[28];
    const float* dn_g1  = (const float*)d_in[29];
    const float* dn_b1  = (const float*)d_in[30];
    const float* dn_w1  = (const float*)d_in[31];
    const float* dn_g2  = (const float*)d_in[32];
    const float* dn_b2  = (const float*)d_in[33];
    const float* dn_w2  = (const float*)d_in[34];
    const float* dn_w3  = (const float*)d_in[35];
    const float* l1_w   = (const float*)d_in[36];
    const float* l1_b   = (const float*)d_in[37];
    const float* l2_w   = (const float*)d_in[38];
    const float* l2_b   = (const float*)d_in[39];

    char* p = (char*)d_ws;
    auto take = [&](size_t elems) -> float* {
        float* r = (float*)p;
        p += ((elems * 4 + 255) / 256) * 256;
        return r;
    };
    float* grid    = take((size_t)B * S3);
    float* mask0   = take((size_t)B * S3);
    float* y0      = take((size_t)B * S3 * C0);
    float* x0s     = take((size_t)NPTS * C0);
    float* t0s     = take((size_t)NPTS * C0);
    float* mask1   = take((size_t)B * S13);
    float* y1      = take((size_t)B * S13 * C1);
    float* x1s     = take((size_t)B * S13 * C1);
    float* t1s     = take((size_t)B * S13 * C1);
    float* partial = take((size_t)NB_STATS * 32);
    float* scsh    = take(32);
    int*   list0   = (int*)take(NPTS);
    int*   list1   = (int*)take((size_t)B * S13);
    int*   cnt     = (int*)take(16);
    int* cnt0 = cnt;
    int* cnt1 = cnt + 1;

    hipMemsetAsync(grid,  0, (size_t)B * S3 * 4, stream);
    hipMemsetAsync(mask0, 0, (size_t)B * S3 * 4, stream);
    hipMemsetAsync(cnt,   0, 8, stream);

    const int GB0 = (NPTS + TS - 1) / TS;
    const int GB1 = (B * S13 + TS - 1) / TS;

    k_scatter<<<GB0, TS, 0, stream>>>(coords, feats, grid, mask0);
    k_list0<<<(B * S3 + TS - 1) / TS, TS, 0, stream>>>(mask0, list0, cnt0);
    k_conv0<<<GB0, TS, 0, stream>>>(grid, list0, cnt0, w0, x0s);
    // initial BN: x = masked_bn(conv0_out, g0, b0); keep sparse copy in x0s
    run_bn<C0>(x0s, g0, b0, cnt0, list0, y0, x0s, NPTS, partial, scsh, stream);

    // basic block ba0: y=bn(x,g1,b1); y=conv(y,w1); y=bn(y,g2,b2); x=x+conv(y,w2)
    run_bn<C0>(x0s, ba0_g1, ba0_b1, cnt0, list0, y0, nullptr, NPTS, partial, scsh, stream);
    k_conv<C0, C0, S><<<GB0, TS, 0, stream>>>(y0, mask0, list0, cnt0, ba0_w1, nullptr, t0s);
    run_bn<C0>(t0s, ba0_g2, ba0_b2, cnt0, list0, y0, nullptr, NPTS, partial, scsh, stream);
    k_conv<C0, C0, S><<<GB0, TS, 0, stream>>>(y0, mask0, list0, cnt0, ba0_w2, x0s, x0s);

    // basic block ba1
    run_bn<C0>(x0s, ba1_g1, ba1_b1, cnt0, list0, y0, nullptr, NPTS, partial, scsh, stream);
    k_conv<C0, C0, S><<<GB0, TS, 0, stream>>>(y0, mask0, list0, cnt0, ba1_w1, nullptr, t0s);
    run_bn<C0>(t0s, ba1_g2, ba1_b2, cnt0, list0, y0, nullptr, NPTS, partial, scsh, stream);
    k_conv<C0, C0, S><<<GB0, TS, 0, stream>>>(y0, mask0, list0, cnt0, ba1_w2, x0s, x0s);

    // downsample: y=bn(x,dn_g1,dn_b1); y1=conv_s2(y,w1); y1=bn(y1,dn_g2,dn_b2);
    //             y1=conv(y1,w2); y2=conv_s2(y,w3); x = y1 + y2
    run_bn<C0>(x0s, dn_g1, dn_b1, cnt0, list0, y0, nullptr, NPTS, partial, scsh, stream);
    k_mask1<<<GB1, TS, 0, stream>>>(mask0, mask1, list1, cnt1);
    k_conv_s2<C0, C1><<<GB1, TS, 0, stream>>>(y0, mask0, list1, cnt1, dn_w1, x1s);
    k_conv_s2<C0, C1><<<GB1, TS, 0, stream>>>(y0, mask0, list1, cnt1, dn_w3, t1s);
    run_bn<C1>(x1s, dn_g2, dn_b2, cnt1, list1, y1, nullptr, B * S13, partial, scsh, stream);
    k_conv<C1, C1, S1><<<GB1, TS, 0, stream>>>(y1, mask1, list1, cnt1, dn_w2, t1s, x1s);

    // basic block bo0
    run_bn<C1>(x1s, bo0_g1, bo0_b1, cnt1, list1, y1, nullptr, B * S13, partial, scsh, stream);
    k_conv<C1, C1, S1><<<GB1, TS, 0, stream>>>(y1, mask1, list1, cnt1, bo0_w1, nullptr, t1s);
    run_bn<C1>(t1s, bo0_g2, bo0_b2, cnt1, list1, y1, nullptr, B * S13, partial, scsh, stream);
    k_conv<C1, C1, S1><<<GB1, TS, 0, stream>>>(y1, mask1, list1, cnt1, bo0_w2, x1s, x1s);

    // basic block bo1
    run_bn<C1>(x1s, bo1_g1, bo1_b1, cnt1, list1, y1, nullptr, B * S13, partial, scsh, stream);
    k_conv<C1, C1, S1><<<GB1, TS, 0, stream>>>(y1, mask1, list1, cnt1, bo1_w1, nullptr, t1s);
    run_bn<C1>(t1s, bo1_g2, bo1_b2, cnt1, list1, y1, nullptr, B * S13, partial, scsh, stream);
    k_conv<C1, C1, S1><<<GB1, TS, 0, stream>>>(y1, mask1, list1, cnt1, bo1_w2, x1s, x1s);

    // head
    k_pool<<<B, TS, 0, stream>>>(x1s, list1, cnt1, l1_w, l1_b, l2_w, l2_b, (float*)d_out);
}

// Round 3
// 605.532 us; speedup vs baseline: 1.8322x; 1.8322x over previous
//
#include <hip/hip_runtime.h>
#include <cmath>

#define TS 256

constexpr int S    = 95;
constexpr int B    = 2;
constexpr int S3   = S * S * S;          // 857375
constexpr int S1   = 47;
constexpr int S13  = S1 * S1 * S1;       // 103823
constexpr int NPTS = 40000;
constexpr int C0   = 8;
constexpr int C1   = 16;
constexpr float EPS = 1e-4f;
constexpr int NB_STATS = 128;

// order-preserving float<->uint encoding (uint compare == float compare)
__device__ __forceinline__ unsigned encf(float f) {
    unsigned b = __float_as_uint(f);
    return (b & 0x80000000u) ? ~b : (b | 0x80000000u);
}
__device__ __forceinline__ float decf(unsigned e) {
    unsigned b = (e & 0x80000000u) ? (e ^ 0x80000000u) : ~e;
    return __uint_as_float(b);
}

// ---------------- scatter + mask + list0 (wave-aggregated append) ----------------
__global__ void k_scatter_list(const int* __restrict__ coords, const float* __restrict__ feats,
                               float* __restrict__ grid, float* __restrict__ mask,
                               int* __restrict__ list, int* __restrict__ cnt) {
    int i = blockIdx.x * blockDim.x + threadIdx.x;
    bool valid = i < NPTS;
    int v = 0;
    if (valid) {
        int x = coords[i * 4 + 0], y = coords[i * 4 + 1], z = coords[i * 4 + 2], b = coords[i * 4 + 3];
        v = ((b * S + x) * S + y) * S + z;
        atomicAdd(&grid[v], feats[i]);
    }
    bool own = false;
    if (valid) {
        unsigned old = atomicExch((unsigned*)&mask[v], __float_as_uint(1.0f));
        own = (old == 0u);
    }
    unsigned long long m = __ballot(own);
    int lane = threadIdx.x & 63;
    int cw = __popcll(m);
    int base = 0;
    if (lane == 0 && cw) base = atomicAdd(cnt, cw);
    base = __shfl(base, 0, 64);
    if (own) list[base + __popcll(m & ((1ull << lane) - 1ull))] = v;
}

// ---------------- conv0: 1 -> 8, SAME, stride 1 ----------------
__global__ void k_conv0(const float* __restrict__ grid,
                        const int* __restrict__ list, const int* __restrict__ cnt,
                        const float* __restrict__ w, float* __restrict__ out) {
    int i = blockIdx.x * blockDim.x + threadIdx.x;
    if (i >= cnt[0]) return;
    int v = list[i];
    int z = v % S; int t = v / S;
    int y = t % S; t /= S;
    int x = t % S; int b = t / S;
    float acc[C0];
#pragma unroll
    for (int c = 0; c < C0; ++c) acc[c] = 0.f;
    for (int kx = 0; kx < 3; ++kx) {
        int xx = x + kx - 1; if ((unsigned)xx >= (unsigned)S) continue;
        for (int ky = 0; ky < 3; ++ky) {
            int yy = y + ky - 1; if ((unsigned)yy >= (unsigned)S) continue;
            for (int kz = 0; kz < 3; ++kz) {
                int zz = z + kz - 1; if ((unsigned)zz >= (unsigned)S) continue;
                int n = ((b * S + xx) * S + yy) * S + zz;
                float g = grid[n];          // grid is exactly 0 off-mask
                if (g != 0.0f) {
                    const float* wp = &w[((kx * 3 + ky) * 3 + kz) * C0];
#pragma unroll
                    for (int c = 0; c < C0; ++c) acc[c] = fmaf(g, wp[c], acc[c]);
                }
            }
        }
    }
#pragma unroll
    for (int c = 0; c < C0; ++c) out[(size_t)i * C0 + c] = acc[c];
}

// ---------------- BN statistics ----------------
template <int C>
__global__ void k_stats(const float* __restrict__ xs, const int* __restrict__ cnt,
                        float* __restrict__ partial) {
    int n = cnt[0];
    float s[2 * C];
#pragma unroll
    for (int c = 0; c < 2 * C; ++c) s[c] = 0.f;
    int stride = gridDim.x * blockDim.x;
    for (int i = blockIdx.x * blockDim.x + threadIdx.x; i < n; i += stride) {
#pragma unroll
        for (int c = 0; c < C; ++c) {
            float v = xs[(size_t)i * C + c];
            s[c] += v;
            s[C + c] += v * v;
        }
    }
#pragma unroll
    for (int c = 0; c < 2 * C; ++c)
        for (int off = 32; off > 0; off >>= 1)
            s[c] += __shfl_down(s[c], off, 64);
    __shared__ float ls[4][2 * C];
    int wv = threadIdx.x >> 6, ln = threadIdx.x & 63;
    if (ln == 0) {
#pragma unroll
        for (int c = 0; c < 2 * C; ++c) ls[wv][c] = s[c];
    }
    __syncthreads();
    if (threadIdx.x < 2 * C) {
        float t = ls[0][threadIdx.x] + ls[1][threadIdx.x] + ls[2][threadIdx.x] + ls[3][threadIdx.x];
        partial[blockIdx.x * (2 * C) + threadIdx.x] = t;
    }
}

// ---------------- BN finalize ----------------
template <int C>
__global__ void k_finalize(const float* __restrict__ partial, const int* __restrict__ cnt,
                           const float* __restrict__ gamma, const float* __restrict__ beta,
                           float* __restrict__ scsh) {
    int c = threadIdx.x;
    if (c >= C) return;
    float s = 0.f, ss = 0.f;
    for (int k = 0; k < NB_STATS; ++k) {
        s  += partial[k * 2 * C + c];
        ss += partial[k * 2 * C + C + c];
    }
    float n = fmaxf((float)cnt[0], 1.0f);
    float mean = s / n;
    float var  = ss / n - mean * mean;
    float sc = gamma[c] * rsqrtf(var + EPS);
    scsh[c]     = sc;
    scsh[C + c] = beta[c] - mean * sc;
}

// ---------------- BN apply + ReLU ----------------
template <int C>
__global__ void k_bnapply(const float* __restrict__ xs, const int* __restrict__ list,
                          const int* __restrict__ cnt, const float* __restrict__ scsh,
                          float* __restrict__ yd, float* __restrict__ xs_out) {
    int i = blockIdx.x * blockDim.x + threadIdx.x;
    if (i >= cnt[0]) return;
    int v = list[i];
#pragma unroll
    for (int c = 0; c < C; ++c) {
        float val = fmaf(scsh[c], xs[(size_t)i * C + c], scsh[C + c]);
        val = fmaxf(val, 0.f);
        yd[(size_t)v * C + c] = val;
        if (xs_out) xs_out[(size_t)i * C + c] = val;
    }
}

// ---------------- generic 3x3x3 SAME stride-1 conv ----------------
template <int CIN, int COUT, int SG>
__global__ void k_conv(const float* __restrict__ y, const float* __restrict__ mask,
                       const int* __restrict__ list, const int* __restrict__ cnt,
                       const float* __restrict__ w, const float* __restrict__ res,
                       float* __restrict__ out) {
    int i = blockIdx.x * blockDim.x + threadIdx.x;
    if (i >= cnt[0]) return;
    int v = list[i];
    int z = v % SG; int t = v / SG;
    int yy = t % SG; t /= SG;
    int x = t % SG; int b = t / SG;
    float acc[COUT];
#pragma unroll
    for (int c = 0; c < COUT; ++c) acc[c] = res ? res[(size_t)i * COUT + c] : 0.f;
    for (int kx = 0; kx < 3; ++kx) {
        int xx = x + kx - 1; if ((unsigned)xx >= (unsigned)SG) continue;
        for (int ky = 0; ky < 3; ++ky) {
            int yn = yy + ky - 1; if ((unsigned)yn >= (unsigned)SG) continue;
            for (int kz = 0; kz < 3; ++kz) {
                int zz = z + kz - 1; if ((unsigned)zz >= (unsigned)SG) continue;
                int n = ((b * SG + xx) * SG + yn) * SG + zz;
                if (mask[n] != 0.f) {
                    const float* yp = &y[(size_t)n * CIN];
                    const float* wp = &w[((kx * 3 + ky) * 3 + kz) * CIN * COUT];
#pragma unroll
                    for (int ci = 0; ci < CIN; ++ci) {
                        float val = yp[ci];
#pragma unroll
                        for (int co = 0; co < COUT; ++co)
                            acc[co] = fmaf(val, wp[ci * COUT + co], acc[co]);
                    }
                }
            }
        }
    }
#pragma unroll
    for (int c = 0; c < COUT; ++c) out[(size_t)i * COUT + c] = acc[c];
}

// ---------------- stride-2 VALID conv, L0 dense -> L1 sparse ----------------
template <int CIN, int COUT>
__global__ void k_conv_s2(const float* __restrict__ y, const float* __restrict__ mask0,
                          const int* __restrict__ list1, const int* __restrict__ cnt1,
                          const float* __restrict__ w, float* __restrict__ out) {
    int i = blockIdx.x * blockDim.x + threadIdx.x;
    if (i >= cnt1[0]) return;
    int v = list1[i];
    int z = v % S1; int t = v / S1;
    int yy = t % S1; t /= S1;
    int x = t % S1; int b = t / S1;
    float acc[COUT];
#pragma unroll
    for (int c = 0; c < COUT; ++c) acc[c] = 0.f;
    for (int kx = 0; kx < 3; ++kx) {
        int xx = 2 * x + kx;
        for (int ky = 0; ky < 3; ++ky) {
            int yn = 2 * yy + ky;
            for (int kz = 0; kz < 3; ++kz) {
                int zz = 2 * z + kz;
                int n = ((b * S + xx) * S + yn) * S + zz;
                if (mask0[n] != 0.f) {
                    const float* yp = &y[(size_t)n * CIN];
                    const float* wp = &w[((kx * 3 + ky) * 3 + kz) * CIN * COUT];
#pragma unroll
                    for (int ci = 0; ci < CIN; ++ci) {
                        float val = yp[ci];
#pragma unroll
                        for (int co = 0; co < COUT; ++co)
                            acc[co] = fmaf(val, wp[ci * COUT + co], acc[co]);
                    }
                }
            }
        }
    }
#pragma unroll
    for (int c = 0; c < COUT; ++c) out[(size_t)i * COUT + c] = acc[c];
}

// ---------------- final conv + fused masked max-pool epilogue ----------------
__global__ void k_conv_pool(const float* __restrict__ y, const float* __restrict__ mask,
                            const int* __restrict__ list, const int* __restrict__ cnt,
                            const float* __restrict__ w, const float* __restrict__ res,
                            unsigned* __restrict__ pooled) {
    __shared__ unsigned sm[B * C1];
    if (threadIdx.x < B * C1) sm[threadIdx.x] = 0u;
    __syncthreads();

    int i = blockIdx.x * blockDim.x + threadIdx.x;
    bool valid = i < cnt[0];
    if (valid) {
        int v = list[i];
        int z = v % S1; int t = v / S1;
        int yy = t % S1; t /= S1;
        int x = t % S1; int b = t / S1;
        float acc[C1];
#pragma unroll
        for (int c = 0; c < C1; ++c) acc[c] = res[(size_t)i * C1 + c];
        for (int kx = 0; kx < 3; ++kx) {
            int xx = x + kx - 1; if ((unsigned)xx >= (unsigned)S1) continue;
            for (int ky = 0; ky < 3; ++ky) {
                int yn = yy + ky - 1; if ((unsigned)yn >= (unsigned)S1) continue;
                for (int kz = 0; kz < 3; ++kz) {
                    int zz = z + kz - 1; if ((unsigned)zz >= (unsigned)S1) continue;
                    int n = ((b * S1 + xx) * S1 + yn) * S1 + zz;
                    if (mask[n] != 0.f) {
                        const float* yp = &y[(size_t)n * C1];
                        const float* wp = &w[((kx * 3 + ky) * 3 + kz) * C1 * C1];
#pragma unroll
                        for (int ci = 0; ci < C1; ++ci) {
                            float val = yp[ci];
#pragma unroll
                            for (int co = 0; co < C1; ++co)
                                acc[co] = fmaf(val, wp[ci * C1 + co], acc[co]);
                        }
                    }
                }
            }
        }
#pragma unroll
        for (int c = 0; c < C1; ++c) atomicMax(&sm[b * C1 + c], encf(acc[c]));
    }
    __syncthreads();
    if (threadIdx.x < B * C1) {
        unsigned e = sm[threadIdx.x];
        if (e) atomicMax(&pooled[threadIdx.x], e);
    }
}

// ---------------- downsampled mask + list (L1), block-aggregated append ----------------
__global__ void k_mask1(const float* __restrict__ mask0, float* __restrict__ mask1,
                        int* __restrict__ list1, int* __restrict__ cnt1) {
    int v = blockIdx.x * blockDim.x + threadIdx.x;
    bool valid = v < B * S13;
    float m = 0.f;
    if (valid) {
        int z = v % S1; int t = v / S1;
        int y = t % S1; t /= S1;
        int x = t % S1; int b = t / S1;
        for (int kx = 0; kx < 3; ++kx)
            for (int ky = 0; ky < 3; ++ky)
                for (int kz = 0; kz < 3; ++kz) {
                    int n = ((b * S + 2 * x + kx) * S + 2 * y + ky) * S + 2 * z + kz;
                    m = fmaxf(m, mask0[n]);
                }
        mask1[v] = m;
    }
    bool pred = valid && (m > 0.f);
    __shared__ int s_w[4];
    unsigned long long bm = __ballot(pred);
    int lane = threadIdx.x & 63, wv = threadIdx.x >> 6;
    int cw = __popcll(bm);
    if (lane == 0) s_w[wv] = cw;
    __syncthreads();
    if (threadIdx.x == 0) {
        int tot = s_w[0] + s_w[1] + s_w[2] + s_w[3];
        int base = tot ? atomicAdd(cnt1, tot) : 0;
        int acc = base;
        for (int k = 0; k < 4; ++k) { int c = s_w[k]; s_w[k] = acc; acc += c; }
    }
    __syncthreads();
    if (pred) list1[s_w[wv] + __popcll(bm & ((1ull << lane) - 1ull))] = v;
}

// ---------------- head: 2-layer MLP on pooled features ----------------
__global__ void k_head(const unsigned* __restrict__ pooled,
                       const float* __restrict__ l1w, const float* __restrict__ l1b,
                       const float* __restrict__ l2w, const float* __restrict__ l2b,
                       float* __restrict__ outp) {
    int t = threadIdx.x;               // 64 threads: b = t>>5, j = t&31
    int b = t >> 5, j = t & 31;
    float h = l1b[j];
#pragma unroll
    for (int c = 0; c < C1; ++c) {
        unsigned e = pooled[b * C1 + c];
        float p = (e == 0u) ? 0.f : decf(e);
        h = fmaf(l1w[j * C1 + c], p, h);
    }
    float val = l2w[j] * h;
#pragma unroll
    for (int off = 16; off > 0; off >>= 1) val += __shfl_down(val, off, 32);
    if (j == 0) outp[b] = val + l2b[0];
}

// ---------------- host-side BN helper ----------------
template <int C>
static void run_bn(const float* xs, const float* g, const float* bt,
                   const int* cntp, const int* listp, float* yd, float* xs_out, int maxn,
                   float* partial, float* scsh, hipStream_t stream) {
    k_stats<C><<<NB_STATS, TS, 0, stream>>>(xs, cntp, partial);
    k_finalize<C><<<1, 64, 0, stream>>>(partial, cntp, g, bt, scsh);
    k_bnapply<C><<<(maxn + TS - 1) / TS, TS, 0, stream>>>(xs, listp, cntp, scsh, yd, xs_out);
}

extern "C" void kernel_launch(void* const* d_in, const int* in_sizes, int n_in,
                              void* d_out, int out_size, void* d_ws, size_t ws_size,
                              hipStream_t stream) {
    const int*   coords = (const int*)  d_in[0];
    const float* feats  = (const float*)d_in[1];
    const float* w0     = (const float*)d_in[2];
    const float* g0     = (const float*)d_in[3];
    const float* b0     = (const float*)d_in[4];
    const float* ba0_g1 = (const float*)d_in[5];
    const float* ba0_b1 = (const float*)d_in[6];
    const float* ba0_w1 = (const float*)d_in[7];
    const float* ba0_g2 = (const float*)d_in[8];
    const float* ba0_b2 = (const float*)d_in[9];
    const float* ba0_w2 = (const float*)d_in[10];
    const float* ba1_g1 = (const float*)d_in[11];
    const float* ba1_b1 = (const float*)d_in[12];
    const float* ba1_w1 = (const float*)d_in[13];
    const float* ba1_g2 = (const float*)d_in[14];
    const float* ba1_b2 = (const float*)d_in[15];
    const float* ba1_w2 = (const float*)d_in[16];
    const float* bo0_g1 = (const float*)d_in[17];
    const float* bo0_b1 = (const float*)d_in[18];
    const float* bo0_w1 = (const float*)d_in[19];
    const float* bo0_g2 = (const float*)d_in[20];
    const float* bo0_b2 = (const float*)d_in[21];
    const float* bo0_w2 = (const float*)d_in[22];
    const float* bo1_g1 = (const float*)d_in[23];
    const float* bo1_b1 = (const float*)d_in[24];
    const float* bo1_w1 = (const float*)d_in[25];
    const float* bo1_g2 = (const float*)d_in[26];
    const float* bo1_b2 = (const float*)d_in[27];
    const float* bo1_w2 = (const float*)d_in[28];
    const float* dn_g1  = (const float*)d_in[29];
    const float* dn_b1  = (const float*)d_in[30];
    const float* dn_w1  = (const float*)d_in[31];
    const float* dn_g2  = (const float*)d_in[32];
    const float* dn_b2  = (const float*)d_in[33];
    const float* dn_w2  = (const float*)d_in[34];
    const float* dn_w3  = (const float*)d_in[35];
    const float* l1_w   = (const float*)d_in[36];
    const float* l1_b   = (const float*)d_in[37];
    const float* l2_w   = (const float*)d_in[38];
    const float* l2_b   = (const float*)d_in[39];

    char* p = (char*)d_ws;
    auto take = [&](size_t elems) -> float* {
        float* r = (float*)p;
        p += ((elems * 4 + 255) / 256) * 256;
        return r;
    };
    float* grid    = take((size_t)B * S3);
    float* mask0   = take((size_t)B * S3);
    float* y0      = take((size_t)B * S3 * C0);
    float* x0s     = take((size_t)NPTS * C0);
    float* t0s     = take((size_t)NPTS * C0);
    float* mask1   = take((size_t)B * S13);
    float* y1      = take((size_t)B * S13 * C1);
    float* x1s     = take((size_t)B * S13 * C1);
    float* t1s     = take((size_t)B * S13 * C1);
    float* partial = take((size_t)NB_STATS * 32);
    float* scsh    = take(32);
    unsigned* pooled = (unsigned*)take(B * C1);
    int*   list0   = (int*)take(NPTS);
    int*   list1   = (int*)take((size_t)B * S13);
    int*   cnt     = (int*)take(16);
    int* cnt0 = cnt;
    int* cnt1 = cnt + 1;

    hipMemsetAsync(grid,  0, (size_t)B * S3 * 4, stream);
    hipMemsetAsync(mask0, 0, (size_t)B * S3 * 4, stream);
    hipMemsetAsync(cnt,   0, 8, stream);
    hipMemsetAsync(pooled, 0, B * C1 * 4, stream);

    const int GB0 = (NPTS + TS - 1) / TS;
    const int GB1 = (B * S13 + TS - 1) / TS;

    k_scatter_list<<<GB0, TS, 0, stream>>>(coords, feats, grid, mask0, list0, cnt0);
    k_conv0<<<GB0, TS, 0, stream>>>(grid, list0, cnt0, w0, x0s);
    // initial BN: x = masked_bn(conv0_out, g0, b0); keep sparse copy in x0s
    run_bn<C0>(x0s, g0, b0, cnt0, list0, y0, x0s, NPTS, partial, scsh, stream);

    // basic block ba0
    run_bn<C0>(x0s, ba0_g1, ba0_b1, cnt0, list0, y0, nullptr, NPTS, partial, scsh, stream);
    k_conv<C0, C0, S><<<GB0, TS, 0, stream>>>(y0, mask0, list0, cnt0, ba0_w1, nullptr, t0s);
    run_bn<C0>(t0s, ba0_g2, ba0_b2, cnt0, list0, y0, nullptr, NPTS, partial, scsh, stream);
    k_conv<C0, C0, S><<<GB0, TS, 0, stream>>>(y0, mask0, list0, cnt0, ba0_w2, x0s, x0s);

    // basic block ba1
    run_bn<C0>(x0s, ba1_g1, ba1_b1, cnt0, list0, y0, nullptr, NPTS, partial, scsh, stream);
    k_conv<C0, C0, S><<<GB0, TS, 0, stream>>>(y0, mask0, list0, cnt0, ba1_w1, nullptr, t0s);
    run_bn<C0>(t0s, ba1_g2, ba1_b2, cnt0, list0, y0, nullptr, NPTS, partial, scsh, stream);
    k_conv<C0, C0, S><<<GB0, TS, 0, stream>>>(y0, mask0, list0, cnt0, ba1_w2, x0s, x0s);

    // downsample
    run_bn<C0>(x0s, dn_g1, dn_b1, cnt0, list0, y0, nullptr, NPTS, partial, scsh, stream);
    k_mask1<<<GB1, TS, 0, stream>>>(mask0, mask1, list1, cnt1);
    k_conv_s2<C0, C1><<<GB1, TS, 0, stream>>>(y0, mask0, list1, cnt1, dn_w1, x1s);
    k_conv_s2<C0, C1><<<GB1, TS, 0, stream>>>(y0, mask0, list1, cnt1, dn_w3, t1s);
    run_bn<C1>(x1s, dn_g2, dn_b2, cnt1, list1, y1, nullptr, B * S13, partial, scsh, stream);
    k_conv<C1, C1, S1><<<GB1, TS, 0, stream>>>(y1, mask1, list1, cnt1, dn_w2, t1s, x1s);

    // basic block bo0
    run_bn<C1>(x1s, bo0_g1, bo0_b1, cnt1, list1, y1, nullptr, B * S13, partial, scsh, stream);
    k_conv<C1, C1, S1><<<GB1, TS, 0, stream>>>(y1, mask1, list1, cnt1, bo0_w1, nullptr, t1s);
    run_bn<C1>(t1s, bo0_g2, bo0_b2, cnt1, list1, y1, nullptr, B * S13, partial, scsh, stream);
    k_conv<C1, C1, S1><<<GB1, TS, 0, stream>>>(y1, mask1, list1, cnt1, bo0_w2, x1s, x1s);

    // basic block bo1
    run_bn<C1>(x1s, bo1_g1, bo1_b1, cnt1, list1, y1, nullptr, B * S13, partial, scsh, stream);
    k_conv<C1, C1, S1><<<GB1, TS, 0, stream>>>(y1, mask1, list1, cnt1, bo1_w1, nullptr, t1s);
    run_bn<C1>(t1s, bo1_g2, bo1_b2, cnt1, list1, y1, nullptr, B * S13, partial, scsh, stream);
    // final conv fused with masked max-pool epilogue
    k_conv_pool<<<GB1, TS, 0, stream>>>(y1, mask1, list1, cnt1, bo1_w2, x1s, pooled);

    // head
    k_head<<<1, 64, 0, stream>>>(pooled, l1_w, l1_b, l2_w, l2_b, (float*)d_out);
}